// Round 1
// baseline (46.946 us; speedup 1.0000x reference)
//
#include <hip/hip_runtime.h>

// SurvivalNLLLoss: hazard [T=128, B=262144] fp32, event_times [B] int,
// censored [B] int(bool). Output: scalar mean loss (fp32).
//
// Per column b:  t = min(event[b], T-1)
//   cum  = sum_{i=0..t} log(1 - h[i,b])
//   loss = censored ? -cum : -(cum - log(1-h[t,b])) - log(h[t,b])
// Answer = mean over b.

static constexpr int T_DIM = 128;
static constexpr float EPS_F = 1e-7f;

// ---------------- pass 1: per-block partial sums -----------------------------
__global__ __launch_bounds__(256) void surv_partial(
    const float* __restrict__ hazard,
    const int* __restrict__ event_times,
    const int* __restrict__ censored,
    float* __restrict__ partials, int B)
{
    const int tid  = blockIdx.x * blockDim.x + threadIdx.x;
    const int col0 = tid * 2;

    float local = 0.0f;
    if (col0 + 1 < B) {
        const int t0 = min(event_times[col0],     T_DIM - 1);
        const int t1 = min(event_times[col0 + 1], T_DIM - 1);

        float cum0 = 0.0f, cum1 = 0.0f;
        float lsa0 = 0.0f, lsa1 = 0.0f;   // log(1-h) at t
        float lha0 = 0.0f, lha1 = 0.0f;   // log(h)   at t

        #pragma unroll 4
        for (int i = 0; i < T_DIM; ++i) {
            const float2 h2 = *reinterpret_cast<const float2*>(
                hazard + (size_t)i * (size_t)B + col0);

            // column 0
            {
                const float h  = fminf(fmaxf(h2.x, EPS_F), 1.0f - EPS_F);
                const float ls = __logf(1.0f - h);
                const float lh = __logf(h);
                if (i <= t0) cum0 += ls;
                if (i == t0) { lsa0 = ls; lha0 = lh; }
            }
            // column 1
            {
                const float h  = fminf(fmaxf(h2.y, EPS_F), 1.0f - EPS_F);
                const float ls = __logf(1.0f - h);
                const float lh = __logf(h);
                if (i <= t1) cum1 += ls;
                if (i == t1) { lsa1 = ls; lha1 = lh; }
            }
        }

        const bool c0 = censored[col0]     != 0;
        const bool c1 = censored[col0 + 1] != 0;
        // uncensored: -(cum - ls_t) - lh_t  =  ls_t - lh_t - cum
        const float l0 = c0 ? -cum0 : (lsa0 - lha0 - cum0);
        const float l1 = c1 ? -cum1 : (lsa1 - lha1 - cum1);
        local = l0 + l1;
    }

    // wave (64-lane) reduction
    #pragma unroll
    for (int off = 32; off > 0; off >>= 1)
        local += __shfl_down(local, off);

    __shared__ float smem[4];
    const int lane = threadIdx.x & 63;
    const int wid  = threadIdx.x >> 6;
    if (lane == 0) smem[wid] = local;
    __syncthreads();
    if (threadIdx.x == 0)
        partials[blockIdx.x] = smem[0] + smem[1] + smem[2] + smem[3];
}

// ---------------- pass 2: deterministic final reduce -------------------------
__global__ __launch_bounds__(256) void surv_final(
    const float* __restrict__ partials, int n,
    float* __restrict__ out, float inv_count)
{
    float local = 0.0f;
    for (int i = threadIdx.x; i < n; i += 256)
        local += partials[i];

    #pragma unroll
    for (int off = 32; off > 0; off >>= 1)
        local += __shfl_down(local, off);

    __shared__ float smem[4];
    const int lane = threadIdx.x & 63;
    const int wid  = threadIdx.x >> 6;
    if (lane == 0) smem[wid] = local;
    __syncthreads();
    if (threadIdx.x == 0)
        out[0] = (smem[0] + smem[1] + smem[2] + smem[3]) * inv_count;
}

extern "C" void kernel_launch(void* const* d_in, const int* in_sizes, int n_in,
                              void* d_out, int out_size, void* d_ws, size_t ws_size,
                              hipStream_t stream)
{
    const float* hazard      = (const float*)d_in[0];
    const int*   event_times = (const int*)d_in[1];
    const int*   censored    = (const int*)d_in[2];
    float*       out         = (float*)d_out;

    const int total = in_sizes[0];          // T*B
    const int B     = in_sizes[1];          // 262144
    (void)total; (void)n_in; (void)out_size; (void)ws_size;

    float* partials = (float*)d_ws;

    const int threads = 256;
    const int cols_per_thread = 2;
    const int nthreads = (B + cols_per_thread - 1) / cols_per_thread;
    const int nblocks  = (nthreads + threads - 1) / threads;   // 512 for B=262144

    surv_partial<<<nblocks, threads, 0, stream>>>(hazard, event_times, censored,
                                                  partials, B);
    surv_final<<<1, threads, 0, stream>>>(partials, nblocks, out, 1.0f / (float)B);
}

// Round 2
// 43.023 us; speedup vs baseline: 1.0912x; 1.0912x over previous
//
#include <hip/hip_runtime.h>

// SurvivalNLLLoss: hazard [T=128, B=262144] fp32, event_times [B] int,
// censored [B] int(bool). Output: scalar mean loss (fp32).
//
// Per column b:  t = min(event[b], T-1)
//   loss = censored ? -sum_{i<=t} ls_i : -(sum_{i<=t} ls_i) + (ls_t - lh_t)
// where ls = log(1-h), lh = log(h), h clamped to [eps, 1-eps].
//
// T is split into NCHUNK row-chunks; each block accumulates its chunk's
// contribution for 512 columns:
//   contrib = -sum_{i in chunk, i<=t} ls_i + [t in chunk]*(cens?0:(ls_t-lh_t))
// Summing contribs over chunks == full loss. 4x more blocks -> 32 waves/CU
// (vs 8 before) to hide HBM latency.

static constexpr int T_DIM  = 128;
static constexpr int NCHUNK = 4;
static constexpr int ROWS   = T_DIM / NCHUNK;   // 32
static constexpr float EPS_F = 1e-7f;

// ---------------- pass 1: per-block partial sums -----------------------------
__global__ __launch_bounds__(256, 8) void surv_partial(
    const float* __restrict__ hazard,
    const int* __restrict__ event_times,
    const int* __restrict__ censored,
    float* __restrict__ partials, int B)
{
    const int tc  = blockIdx.x % NCHUNK;          // T-chunk index
    const int cb  = blockIdx.x / NCHUNK;          // column-block index
    const int col0 = (cb * 256 + threadIdx.x) * 2;
    const int r0   = tc * ROWS;

    float local = 0.0f;
    if (col0 + 1 < B) {
        const int t0 = min(event_times[col0],     T_DIM - 1);
        const int t1 = min(event_times[col0 + 1], T_DIM - 1);

        float acc0 = 0.0f, acc1 = 0.0f;   // sum of ls over rows in chunk, i<=t
        float e0   = 0.0f, e1   = 0.0f;   // (ls_t - lh_t) if t in chunk

        const float* p = hazard + (size_t)r0 * (size_t)B + col0;

        #pragma unroll 8
        for (int i = 0; i < ROWS; ++i) {
            const float2 h2 = *reinterpret_cast<const float2*>(
                p + (size_t)i * (size_t)B);
            const int row = r0 + i;

            {
                const float h  = fminf(fmaxf(h2.x, EPS_F), 1.0f - EPS_F);
                const float ls = __logf(1.0f - h);
                const float lh = __logf(h);
                acc0 += (row <= t0) ? ls : 0.0f;
                e0   += (row == t0) ? (ls - lh) : 0.0f;
            }
            {
                const float h  = fminf(fmaxf(h2.y, EPS_F), 1.0f - EPS_F);
                const float ls = __logf(1.0f - h);
                const float lh = __logf(h);
                acc1 += (row <= t1) ? ls : 0.0f;
                e1   += (row == t1) ? (ls - lh) : 0.0f;
            }
        }

        const bool c0 = censored[col0]     != 0;
        const bool c1 = censored[col0 + 1] != 0;
        const float l0 = c0 ? -acc0 : (e0 - acc0);
        const float l1 = c1 ? -acc1 : (e1 - acc1);
        local = l0 + l1;
    }

    // wave (64-lane) reduction
    #pragma unroll
    for (int off = 32; off > 0; off >>= 1)
        local += __shfl_down(local, off);

    __shared__ float smem[4];
    const int lane = threadIdx.x & 63;
    const int wid  = threadIdx.x >> 6;
    if (lane == 0) smem[wid] = local;
    __syncthreads();
    if (threadIdx.x == 0)
        partials[blockIdx.x] = smem[0] + smem[1] + smem[2] + smem[3];
}

// ---------------- pass 2: deterministic final reduce -------------------------
__global__ __launch_bounds__(256) void surv_final(
    const float* __restrict__ partials, int n,
    float* __restrict__ out, float inv_count)
{
    float local = 0.0f;
    for (int i = threadIdx.x; i < n; i += 256)
        local += partials[i];

    #pragma unroll
    for (int off = 32; off > 0; off >>= 1)
        local += __shfl_down(local, off);

    __shared__ float smem[4];
    const int lane = threadIdx.x & 63;
    const int wid  = threadIdx.x >> 6;
    if (lane == 0) smem[wid] = local;
    __syncthreads();
    if (threadIdx.x == 0)
        out[0] = (smem[0] + smem[1] + smem[2] + smem[3]) * inv_count;
}

extern "C" void kernel_launch(void* const* d_in, const int* in_sizes, int n_in,
                              void* d_out, int out_size, void* d_ws, size_t ws_size,
                              hipStream_t stream)
{
    const float* hazard      = (const float*)d_in[0];
    const int*   event_times = (const int*)d_in[1];
    const int*   censored    = (const int*)d_in[2];
    float*       out         = (float*)d_out;

    const int B = in_sizes[1];              // 262144
    (void)n_in; (void)out_size; (void)ws_size;

    float* partials = (float*)d_ws;

    const int threads = 256;
    const int cols_per_block = threads * 2;                         // 512
    const int col_blocks = (B + cols_per_block - 1) / cols_per_block; // 512
    const int nblocks = col_blocks * NCHUNK;                        // 2048

    surv_partial<<<nblocks, threads, 0, stream>>>(hazard, event_times, censored,
                                                  partials, B);
    surv_final<<<1, threads, 0, stream>>>(partials, nblocks, out, 1.0f / (float)B);
}